// Round 3
// baseline (2384.577 us; speedup 1.0000x reference)
//
#include <hip/hip_runtime.h>
#include <stdint.h>

// SparseAttentionMaskGenerator: per-(b,h) 0.95-quantile threshold mask.
// mask = scores >= x_(K_SEL) per head (0-indexed ascending order statistic);
// bit-exact vs jnp/np linear-interpolated quantile (thr lies in (x[k],x[k+1]]
// and no value exists strictly between adjacent order statistics).
// Output: bool mask materialized as int32 0/1.
//
// Structure (2 full passes over the 256 MiB input):
//   k_zero    : zero hist/cnt/cov scratch (own kernel; rocclr fill was 157us!)
//   k_hist    : per-head 2048-bin mantissa histogram of [1,2) + windowed
//               candidate collection (bins [WLO,WHI], ~13K/head expected)
//   k_selbin  : prefix-scan -> target bin + residual rank; coverage flag
//   k_collect : fallback full scan, no-op when window covered (always, in practice)
//   k_thr     : tie-aware rank select among target-bin candidates
//   k_mask    : out = scores >= thr[h]

#define NUM_HEADS 16
#define PER_HEAD (1u << 22)          // 2048*2048 elements per head
#define K_SEL 3984588u               // floor(0.95*(N-1)) + 1
#define NBINS 2050                   // [0]=x<1.0, [1..2048]=mantissa bins, [2049]=x>=2.0
#define HIST_STRIDE 2052
#define CAND_CAP 16384
#define WLO 1291                     // bin of ~1.6299
#define WHI 1352                     // bin of ~1.6602  (quantile ~1.6449 +- 0.0010)
#define FILT_CAP 1024

// ws layout (bytes):
#define OFF_CNT  131328              // hist u32[16][2052] = 131328 B at 0
#define OFF_CNT2 131392              // u32[16]
#define OFF_COV  131456              // u32[16]
#define OFF_SEL  131520              // u32[16][2]
#define OFF_THR  131648              // f32[16]
#define OFF_CAND 131712              // f32[16][CAND_CAP] = 1 MiB
#define ZERO_BYTES 131520            // hist + cnt + cnt2 + cov (16B-multiple)

__device__ __forceinline__ int bin_of(float x) {
    if (x < 1.0f) return 0;
    if (x >= 2.0f) return NBINS - 1;
    return 1 + (int)((__float_as_uint(x) >> 12) & 0x7FFu);  // mantissa[22:12]
}

__global__ void k_zero(uint32_t* __restrict__ ws) {
    uint4* p = (uint4*)ws;
    const uint32_t n4 = ZERO_BYTES / 16;
    for (uint32_t i = blockIdx.x * blockDim.x + threadIdx.x; i < n4;
         i += gridDim.x * blockDim.x)
        p[i] = make_uint4(0u, 0u, 0u, 0u);
}

__global__ void k_hist(const float* __restrict__ scores, uint32_t* __restrict__ hist,
                       uint32_t* __restrict__ cnt, float* __restrict__ cand) {
    __shared__ uint32_t lh[NBINS];
    const int h = blockIdx.y;
    for (int i = threadIdx.x; i < NBINS; i += blockDim.x) lh[i] = 0;
    __syncthreads();
    const float4* p = (const float4*)(scores + (size_t)h * PER_HEAD);
    const uint32_t nvec = PER_HEAD / 4;
    uint32_t c_lo = 0, c_hi = 0;  // register-aggregate the huge tail bins
    for (uint32_t i = blockIdx.x * blockDim.x + threadIdx.x; i < nvec;
         i += gridDim.x * blockDim.x) {
        float4 v = p[i];
        float xs[4] = {v.x, v.y, v.z, v.w};
#pragma unroll
        for (int j = 0; j < 4; ++j) {
            float x = xs[j];
            if (x < 1.0f) { c_lo++; continue; }
            if (x >= 2.0f) { c_hi++; continue; }
            int b = 1 + (int)((__float_as_uint(x) >> 12) & 0x7FFu);
            atomicAdd(&lh[b], 1u);
            if (b >= WLO && b <= WHI) {           // ~0.3% of elements
                uint32_t pos = atomicAdd(&cnt[h], 1u);
                if (pos < CAND_CAP) cand[h * CAND_CAP + pos] = x;
            }
        }
    }
    atomicAdd(&lh[0], c_lo);
    atomicAdd(&lh[NBINS - 1], c_hi);
    __syncthreads();
    for (int i = threadIdx.x; i < NBINS; i += blockDim.x)
        if (lh[i]) atomicAdd(&hist[h * HIST_STRIDE + i], lh[i]);
}

__global__ void k_selbin(const uint32_t* __restrict__ hist, const uint32_t* __restrict__ cnt,
                         uint32_t* __restrict__ sel, uint32_t* __restrict__ cov) {
    const int h = blockIdx.x;
    if (threadIdx.x != 0) return;
    const uint32_t* hh = hist + h * HIST_STRIDE;
    uint64_t cum = 0;
    for (int b = 0; b < NBINS; ++b) {
        uint64_t nxt = cum + hh[b];
        if ((uint64_t)K_SEL < nxt) {
            sel[h * 2]     = (uint32_t)b;
            sel[h * 2 + 1] = (uint32_t)(K_SEL - cum);
            cov[h] = (b >= WLO && b <= WHI && cnt[h] <= CAND_CAP) ? 1u : 0u;
            return;
        }
        cum = nxt;
    }
}

// Fallback only — no-op when the window covered the target bin (the expected case).
__global__ void k_collect(const float* __restrict__ scores, const uint32_t* __restrict__ sel,
                          const uint32_t* __restrict__ cov, uint32_t* __restrict__ cnt2,
                          float* __restrict__ cand) {
    const int h = blockIdx.y;
    if (cov[h]) return;
    const int target = (int)sel[h * 2];
    const float4* p = (const float4*)(scores + (size_t)h * PER_HEAD);
    const uint32_t nvec = PER_HEAD / 4;
    for (uint32_t i = blockIdx.x * blockDim.x + threadIdx.x; i < nvec;
         i += gridDim.x * blockDim.x) {
        float4 v = p[i];
        float xs[4] = {v.x, v.y, v.z, v.w};
#pragma unroll
        for (int j = 0; j < 4; ++j) {
            if (bin_of(xs[j]) == target) {
                uint32_t pos = atomicAdd(&cnt2[h], 1u);
                if (pos < CAND_CAP) cand[h * CAND_CAP + pos] = xs[j];
            }
        }
    }
}

__global__ void k_thr(const uint32_t* __restrict__ sel, const uint32_t* __restrict__ cov,
                      const uint32_t* __restrict__ cnt, const uint32_t* __restrict__ cnt2,
                      const float* __restrict__ cand, float* __restrict__ thr) {
    const int h = blockIdx.x;
    __shared__ float fc[FILT_CAP];
    __shared__ uint32_t lcnt;
    if (threadIdx.x == 0) lcnt = 0;
    __syncthreads();
    const int b = (int)sel[h * 2];
    const uint32_t r = sel[h * 2 + 1];
    const uint32_t n = min(cov[h] ? cnt[h] : cnt2[h], (uint32_t)CAND_CAP);
    // Filter candidates down to the exact target bin (complete set on both paths).
    for (uint32_t i = threadIdx.x; i < n; i += blockDim.x) {
        float x = cand[h * CAND_CAP + i];
        if (bin_of(x) == b) {
            uint32_t pos = atomicAdd(&lcnt, 1u);
            if (pos < FILT_CAP) fc[pos] = x;
        }
    }
    __syncthreads();
    const uint32_t m = min(lcnt, (uint32_t)FILT_CAP);
    // Tie-aware rank selection — order-independent of append order.
    for (uint32_t i = threadIdx.x; i < m; i += blockDim.x) {
        float x = fc[i];
        uint32_t less = 0, eq = 0;
        for (uint32_t j = 0; j < m; ++j) {
            float y = fc[j];
            less += (y < x);
            eq += (y == x);
        }
        if (less <= r && r < less + eq) thr[h] = x;
    }
}

__global__ void k_mask(const float* __restrict__ scores, const float* __restrict__ thr,
                       int* __restrict__ out) {
    const int h = blockIdx.y;
    __shared__ float st;
    if (threadIdx.x == 0) st = thr[h];
    __syncthreads();
    const float t = st;
    const float4* p = (const float4*)(scores + (size_t)h * PER_HEAD);
    int4* o = (int4*)(out + (size_t)h * PER_HEAD);
    const uint32_t nvec = PER_HEAD / 4;
    for (uint32_t i = blockIdx.x * blockDim.x + threadIdx.x; i < nvec;
         i += gridDim.x * blockDim.x) {
        float4 v = p[i];
        int4 m;
        m.x = (v.x >= t) ? 1 : 0;
        m.y = (v.y >= t) ? 1 : 0;
        m.z = (v.z >= t) ? 1 : 0;
        m.w = (v.w >= t) ? 1 : 0;
        o[i] = m;
    }
}

extern "C" void kernel_launch(void* const* d_in, const int* in_sizes, int n_in,
                              void* d_out, int out_size, void* d_ws, size_t ws_size,
                              hipStream_t stream) {
    const float* scores = (const float*)d_in[0];
    int* out = (int*)d_out;
    uint8_t* ws = (uint8_t*)d_ws;

    uint32_t* hist = (uint32_t*)ws;
    uint32_t* cnt  = (uint32_t*)(ws + OFF_CNT);
    uint32_t* cnt2 = (uint32_t*)(ws + OFF_CNT2);
    uint32_t* cov  = (uint32_t*)(ws + OFF_COV);
    uint32_t* sel  = (uint32_t*)(ws + OFF_SEL);
    float*    thr  = (float*)(ws + OFF_THR);
    float*    cand = (float*)(ws + OFF_CAND);

    dim3 blk(256);
    k_zero<<<32, blk, 0, stream>>>((uint32_t*)ws);
    k_hist<<<dim3(256, NUM_HEADS), blk, 0, stream>>>(scores, hist, cnt, cand);
    k_selbin<<<NUM_HEADS, 64, 0, stream>>>(hist, cnt, sel, cov);
    k_collect<<<dim3(256, NUM_HEADS), blk, 0, stream>>>(scores, sel, cov, cnt2, cand);
    k_thr<<<NUM_HEADS, 256, 0, stream>>>(sel, cov, cnt, cnt2, cand, thr);
    k_mask<<<dim3(1024, NUM_HEADS), blk, 0, stream>>>(scores, thr, out);
}

// Round 4
// 320.948 us; speedup vs baseline: 7.4298x; 7.4298x over previous
//
#include <hip/hip_runtime.h>
#include <stdint.h>

// SparseAttentionMaskGenerator: per-(b,h) 0.95-quantile threshold mask.
// mask = scores >= x_(K_SEL) per head (0-indexed ascending order statistic);
// bit-exact vs jnp/np linear-interpolated quantile.
// Output: bool mask materialized as int32 0/1.
//
// R3 lesson: 210K contended global atomicAdds on one cache line = 2.1 ms.
// Candidate append is now block-aggregated: LDS staging buffer + ONE global
// atomicAdd per block (4096 total), bulk copy after reservation.

#define NUM_HEADS 16
#define PER_HEAD (1u << 22)          // 2048*2048 elements per head
#define K_SEL 3984588u               // floor(0.95*(N-1)) + 1
#define NBINS 2050                   // [0]=x<1.0, [1..2048]=mantissa bins, [2049]=x>=2.0
#define HIST_STRIDE 2052
#define CAND_CAP 16384
#define WLO 1291                     // bin of ~1.6299
#define WHI 1352                     // bin of ~1.6602  (quantile ~1.6449 +- ~0.0010 => +-2 bins)
#define WBUF_CAP 384                 // per-block staging; lambda ~51, P(overflow) ~ 0
#define OVERFLOW_POISON 0x08000000u  // forces cov=0 -> exact full-scan fallback
#define FILT_CAP 1024

// ws layout (bytes):
#define OFF_CNT  131328              // hist u32[16][2052] = 131328 B at 0
#define OFF_CNT2 131392              // u32[16]
#define OFF_COV  131456              // u32[16]
#define OFF_SEL  131520              // u32[16][2]
#define OFF_THR  131648              // f32[16]
#define OFF_CAND 131712              // f32[16][CAND_CAP] = 1 MiB
#define ZERO_BYTES 131520            // hist + cnt + cnt2 + cov (16B-multiple)

__device__ __forceinline__ int bin_of(float x) {
    if (x < 1.0f) return 0;
    if (x >= 2.0f) return NBINS - 1;
    return 1 + (int)((__float_as_uint(x) >> 12) & 0x7FFu);  // mantissa[22:12]
}

__global__ void k_zero(uint32_t* __restrict__ ws) {
    uint4* p = (uint4*)ws;
    const uint32_t n4 = ZERO_BYTES / 16;
    for (uint32_t i = blockIdx.x * blockDim.x + threadIdx.x; i < n4;
         i += gridDim.x * blockDim.x)
        p[i] = make_uint4(0u, 0u, 0u, 0u);
}

__global__ void k_hist(const float* __restrict__ scores, uint32_t* __restrict__ hist,
                       uint32_t* __restrict__ cnt, float* __restrict__ cand) {
    __shared__ uint32_t lh[NBINS];
    __shared__ float wbuf[WBUF_CAP];
    __shared__ uint32_t wcnt, wbase;
    const int h = blockIdx.y;
    for (int i = threadIdx.x; i < NBINS; i += blockDim.x) lh[i] = 0;
    if (threadIdx.x == 0) wcnt = 0;
    __syncthreads();
    const float4* p = (const float4*)(scores + (size_t)h * PER_HEAD);
    const uint32_t nvec = PER_HEAD / 4;
    uint32_t c_lo = 0, c_hi = 0;  // register-aggregate the huge tail bins
    for (uint32_t i = blockIdx.x * blockDim.x + threadIdx.x; i < nvec;
         i += gridDim.x * blockDim.x) {
        float4 v = p[i];
        float xs[4] = {v.x, v.y, v.z, v.w};
#pragma unroll
        for (int j = 0; j < 4; ++j) {
            float x = xs[j];
            if (x < 1.0f) { c_lo++; continue; }
            if (x >= 2.0f) { c_hi++; continue; }
            int b = 1 + (int)((__float_as_uint(x) >> 12) & 0x7FFu);
            atomicAdd(&lh[b], 1u);
            if (b >= WLO && b <= WHI) {           // ~0.31% of elements -> LDS staging
                uint32_t pos = atomicAdd(&wcnt, 1u);
                if (pos < WBUF_CAP) wbuf[pos] = x;
            }
        }
    }
    atomicAdd(&lh[0], c_lo);
    atomicAdd(&lh[NBINS - 1], c_hi);
    __syncthreads();
    for (int i = threadIdx.x; i < NBINS; i += blockDim.x)
        if (lh[i]) atomicAdd(&hist[h * HIST_STRIDE + i], lh[i]);
    // Block-aggregated candidate reservation: ONE global atomic per block.
    if (threadIdx.x == 0) {
        uint32_t nc = wcnt;
        uint32_t take = min(nc, (uint32_t)WBUF_CAP);
        uint32_t extra = (nc > WBUF_CAP) ? OVERFLOW_POISON : 0u;
        wbase = atomicAdd(&cnt[h], take + extra);
    }
    __syncthreads();
    const uint32_t nc = min(wcnt, (uint32_t)WBUF_CAP);
    const uint32_t base = wbase;
    for (uint32_t i = threadIdx.x; i < nc; i += blockDim.x) {
        uint32_t pos = base + i;
        if (pos < CAND_CAP) cand[h * CAND_CAP + pos] = wbuf[i];
    }
}

__global__ void k_selbin(const uint32_t* __restrict__ hist, const uint32_t* __restrict__ cnt,
                         uint32_t* __restrict__ sel, uint32_t* __restrict__ cov) {
    const int h = blockIdx.x;
    if (threadIdx.x != 0) return;
    const uint32_t* hh = hist + h * HIST_STRIDE;
    uint64_t cum = 0;
    for (int b = 0; b < NBINS; ++b) {
        uint64_t nxt = cum + hh[b];
        if ((uint64_t)K_SEL < nxt) {
            sel[h * 2]     = (uint32_t)b;
            sel[h * 2 + 1] = (uint32_t)(K_SEL - cum);
            // covered iff target bin inside window AND no overflow/poison
            cov[h] = (b >= WLO && b <= WHI && cnt[h] <= CAND_CAP) ? 1u : 0u;
            return;
        }
        cum = nxt;
    }
}

// Fallback only — no-op when the window covered the target bin (the expected case).
__global__ void k_collect(const float* __restrict__ scores, const uint32_t* __restrict__ sel,
                          const uint32_t* __restrict__ cov, uint32_t* __restrict__ cnt2,
                          float* __restrict__ cand) {
    const int h = blockIdx.y;
    if (cov[h]) return;
    __shared__ float wbuf[WBUF_CAP];
    __shared__ uint32_t wcnt, wbase;
    if (threadIdx.x == 0) wcnt = 0;
    __syncthreads();
    const int target = (int)sel[h * 2];
    const float4* p = (const float4*)(scores + (size_t)h * PER_HEAD);
    const uint32_t nvec = PER_HEAD / 4;
    for (uint32_t i = blockIdx.x * blockDim.x + threadIdx.x; i < nvec;
         i += gridDim.x * blockDim.x) {
        float4 v = p[i];
        float xs[4] = {v.x, v.y, v.z, v.w};
#pragma unroll
        for (int j = 0; j < 4; ++j) {
            if (bin_of(xs[j]) == target) {        // ~210/head -> ~1/block
                uint32_t pos = atomicAdd(&wcnt, 1u);
                if (pos < WBUF_CAP) wbuf[pos] = xs[j];
            }
        }
    }
    __syncthreads();
    if (threadIdx.x == 0) wbase = atomicAdd(&cnt2[h], min(wcnt, (uint32_t)WBUF_CAP));
    __syncthreads();
    const uint32_t nc = min(wcnt, (uint32_t)WBUF_CAP);
    for (uint32_t i = threadIdx.x; i < nc; i += blockDim.x) {
        uint32_t pos = wbase + i;
        if (pos < CAND_CAP) cand[h * CAND_CAP + pos] = wbuf[i];
    }
}

__global__ void k_thr(const uint32_t* __restrict__ sel, const uint32_t* __restrict__ cov,
                      const uint32_t* __restrict__ cnt, const uint32_t* __restrict__ cnt2,
                      const float* __restrict__ cand, float* __restrict__ thr) {
    const int h = blockIdx.x;
    __shared__ float fc[FILT_CAP];
    __shared__ uint32_t lcnt;
    if (threadIdx.x == 0) lcnt = 0;
    __syncthreads();
    const int b = (int)sel[h * 2];
    const uint32_t r = sel[h * 2 + 1];
    const uint32_t n = min(cov[h] ? cnt[h] : cnt2[h], (uint32_t)CAND_CAP);
    // Filter candidates down to the exact target bin (complete set on both paths).
    for (uint32_t i = threadIdx.x; i < n; i += blockDim.x) {
        float x = cand[h * CAND_CAP + i];
        if (bin_of(x) == b) {
            uint32_t pos = atomicAdd(&lcnt, 1u);
            if (pos < FILT_CAP) fc[pos] = x;
        }
    }
    __syncthreads();
    const uint32_t m = min(lcnt, (uint32_t)FILT_CAP);
    // Tie-aware rank selection — order-independent of append order.
    for (uint32_t i = threadIdx.x; i < m; i += blockDim.x) {
        float x = fc[i];
        uint32_t less = 0, eq = 0;
        for (uint32_t j = 0; j < m; ++j) {
            float y = fc[j];
            less += (y < x);
            eq += (y == x);
        }
        if (less <= r && r < less + eq) thr[h] = x;
    }
}

__global__ void k_mask(const float* __restrict__ scores, const float* __restrict__ thr,
                       int* __restrict__ out) {
    const int h = blockIdx.y;
    __shared__ float st;
    if (threadIdx.x == 0) st = thr[h];
    __syncthreads();
    const float t = st;
    const float4* p = (const float4*)(scores + (size_t)h * PER_HEAD);
    int4* o = (int4*)(out + (size_t)h * PER_HEAD);
    const uint32_t nvec = PER_HEAD / 4;
    for (uint32_t i = blockIdx.x * blockDim.x + threadIdx.x; i < nvec;
         i += gridDim.x * blockDim.x) {
        float4 v = p[i];
        int4 m;
        m.x = (v.x >= t) ? 1 : 0;
        m.y = (v.y >= t) ? 1 : 0;
        m.z = (v.z >= t) ? 1 : 0;
        m.w = (v.w >= t) ? 1 : 0;
        o[i] = m;
    }
}

extern "C" void kernel_launch(void* const* d_in, const int* in_sizes, int n_in,
                              void* d_out, int out_size, void* d_ws, size_t ws_size,
                              hipStream_t stream) {
    const float* scores = (const float*)d_in[0];
    int* out = (int*)d_out;
    uint8_t* ws = (uint8_t*)d_ws;

    uint32_t* hist = (uint32_t*)ws;
    uint32_t* cnt  = (uint32_t*)(ws + OFF_CNT);
    uint32_t* cnt2 = (uint32_t*)(ws + OFF_CNT2);
    uint32_t* cov  = (uint32_t*)(ws + OFF_COV);
    uint32_t* sel  = (uint32_t*)(ws + OFF_SEL);
    float*    thr  = (float*)(ws + OFF_THR);
    float*    cand = (float*)(ws + OFF_CAND);

    dim3 blk(256);
    k_zero<<<32, blk, 0, stream>>>((uint32_t*)ws);
    k_hist<<<dim3(256, NUM_HEADS), blk, 0, stream>>>(scores, hist, cnt, cand);
    k_selbin<<<NUM_HEADS, 64, 0, stream>>>(hist, cnt, sel, cov);
    k_collect<<<dim3(256, NUM_HEADS), blk, 0, stream>>>(scores, sel, cov, cnt2, cand);
    k_thr<<<NUM_HEADS, 256, 0, stream>>>(sel, cov, cnt, cnt2, cand, thr);
    k_mask<<<dim3(1024, NUM_HEADS), blk, 0, stream>>>(scores, thr, out);
}

// Round 6
// 185.818 us; speedup vs baseline: 12.8328x; 1.7272x over previous
//
#include <hip/hip_runtime.h>
#include <stdint.h>

// SparseAttentionMaskGenerator: per-(b,h) 0.95-quantile threshold mask.
// mask = scores >= x_(K_SEL) per head (0-indexed ascending order statistic);
// bit-exact vs jnp/np linear-interpolated quantile. Output: int32 0/1.
//
// No histogram work in the hot pass:
//   k_hist: count x < WSTART (registers) + stage window candidates (LDS, one
//           global atomic per block). Coverage test is exact:
//           covered <=> 0 <= K_SEL - below[h] < ncand[h].
//   k_select: bin the ~13K candidates/head (62 LDS bins), rank-select.
//   k_fallback: exact per-head full rescan, no-op when covered (always).
//   k_mask: out = scores >= thr[h], nontemporal stores (native vec type).

#define NUM_HEADS 16
#define PER_HEAD (1u << 22)          // 2048*2048 per head
#define K_SEL 3984588u               // floor(0.95*(N-1)) + 1
#define WSTART 1.6298828125f         // 1 + 1290/2048 (exact float)
#define WEND   1.66015625f           // 1 + 1352/2048 (exact float)
#define WBIN0 1290
#define WBINS 62                     // quantile 1.6449 +- ~0.001; window +-15 bins
#define CAND_CAP 16384               // expected ~13.0K/head
#define WBUF_CAP 384                 // per-block staging; lambda ~51
#define OVERFLOW_POISON 0x08000000u
#define FILT_CAP 768                 // target-bin candidates ~210 expected
#define NBINS_FB 2050

typedef int  int4v  __attribute__((ext_vector_type(4)));
typedef float float4v __attribute__((ext_vector_type(4)));

// ws layout (bytes): below u32[16] @0, cnt u32[16] @64, cov u32[16] @128,
//                    thr f32[16] @192, cand f32[16][CAND_CAP] @256
#define OFF_CNT   64
#define OFF_COV   128
#define OFF_THR   192
#define OFF_CAND  256
#define ZERO_WORDS 48                // below+cnt+cov (thr always written later)

__global__ void k_zero(uint32_t* __restrict__ ws) {
    if (threadIdx.x < ZERO_WORDS) ws[threadIdx.x] = 0u;
}

__global__ void k_hist(const float* __restrict__ scores, uint32_t* __restrict__ below,
                       uint32_t* __restrict__ cnt, float* __restrict__ cand) {
    __shared__ float wbuf[WBUF_CAP];
    __shared__ uint32_t wcnt, wbase;
    __shared__ uint32_t wavesum[4];
    const int h = blockIdx.y;
    if (threadIdx.x == 0) wcnt = 0;
    __syncthreads();
    const float4v* p = (const float4v*)(scores + (size_t)h * PER_HEAD);
    const uint32_t nvec = PER_HEAD / 4;
    uint32_t nb = 0;
    for (uint32_t i = blockIdx.x * blockDim.x + threadIdx.x; i < nvec;
         i += gridDim.x * blockDim.x) {
        float4v v = p[i];
#pragma unroll
        for (int j = 0; j < 4; ++j) {
            float x = v[j];
            nb += (x < WSTART) ? 1u : 0u;
            if (x >= WSTART && x < WEND) {        // ~0.31% of elements
                uint32_t pos = atomicAdd(&wcnt, 1u);
                if (pos < WBUF_CAP) wbuf[pos] = x;
            }
        }
    }
    // wave64 reduce + cross-wave LDS reduce of the below-count
#pragma unroll
    for (int off = 32; off > 0; off >>= 1) nb += __shfl_down(nb, off, 64);
    const int lane = threadIdx.x & 63, wid = threadIdx.x >> 6;
    if (lane == 0) wavesum[wid] = nb;
    __syncthreads();
    if (threadIdx.x == 0) {
        atomicAdd(&below[h], wavesum[0] + wavesum[1] + wavesum[2] + wavesum[3]);
        uint32_t nc = wcnt;
        uint32_t take = min(nc, (uint32_t)WBUF_CAP);
        uint32_t extra = (nc > WBUF_CAP) ? OVERFLOW_POISON : 0u;  // forces fallback
        wbase = atomicAdd(&cnt[h], take + extra);
    }
    __syncthreads();
    const uint32_t nc = min(wcnt, (uint32_t)WBUF_CAP);
    const uint32_t base = wbase;
    for (uint32_t i = threadIdx.x; i < nc; i += blockDim.x) {
        uint32_t pos = base + i;
        if (pos < CAND_CAP) cand[h * CAND_CAP + pos] = wbuf[i];
    }
}

__global__ void k_select(const uint32_t* __restrict__ below, const uint32_t* __restrict__ cnt,
                         const float* __restrict__ cand, uint32_t* __restrict__ cov,
                         float* __restrict__ thr) {
    const int h = blockIdx.x;
    __shared__ uint32_t wh[WBINS];
    __shared__ float fc[FILT_CAP];
    __shared__ uint32_t lcnt, bad;
    __shared__ int sbin;
    __shared__ uint32_t sres;
    const uint32_t craw = cnt[h];
    const long long r = (long long)K_SEL - (long long)below[h];
    // exact coverage test: quantile element is among the staged candidates
    if (craw > CAND_CAP || r < 0 || r >= (long long)craw) {
        if (threadIdx.x == 0) cov[h] = 0u;      // -> fallback
        return;
    }
    const uint32_t n = craw;
    for (int i = threadIdx.x; i < WBINS; i += blockDim.x) wh[i] = 0;
    if (threadIdx.x == 0) { lcnt = 0; bad = 0; }
    __syncthreads();
    for (uint32_t i = threadIdx.x; i < n; i += blockDim.x) {
        float x = cand[h * CAND_CAP + i];
        int b = (int)((__float_as_uint(x) >> 12) & 0x7FFu) - WBIN0;  // all in [0,WBINS)
        atomicAdd(&wh[b], 1u);
    }
    __syncthreads();
    if (threadIdx.x == 0) {
        uint32_t cum = 0, res = 0;
        int b = 0;
        for (; b < WBINS; ++b) {
            uint32_t nx = cum + wh[b];
            if ((uint32_t)r < nx) { res = (uint32_t)r - cum; break; }
            cum = nx;
        }
        sbin = b; sres = res;
        if (wh[b] > FILT_CAP) { bad = 1; cov[h] = 0u; }   // paranoid: filter overflow
    }
    __syncthreads();
    if (bad) return;
    const int tb = sbin;
    const uint32_t r2 = sres;
    for (uint32_t i = threadIdx.x; i < n; i += blockDim.x) {
        float x = cand[h * CAND_CAP + i];
        int b = (int)((__float_as_uint(x) >> 12) & 0x7FFu) - WBIN0;
        if (b == tb) { uint32_t pos = atomicAdd(&lcnt, 1u); if (pos < FILT_CAP) fc[pos] = x; }
    }
    __syncthreads();
    const uint32_t m = lcnt;   // == wh[tb] <= FILT_CAP
    // Tie-aware rank selection — order-independent of append order.
    for (uint32_t i = threadIdx.x; i < m; i += blockDim.x) {
        float x = fc[i];
        uint32_t less = 0, eq = 0;
        for (uint32_t j = 0; j < m; ++j) {
            float y = fc[j];
            less += (y < x);
            eq += (y == x);
        }
        if (less <= r2 && r2 < less + eq) thr[h] = x;
    }
    __syncthreads();
    if (threadIdx.x == 0) cov[h] = 1u;
}

// Exact per-head fallback; never taken for this fixed input (coverage margin
// ~15 sigma). Slow-but-correct: one block rescans its head twice.
__global__ void k_fallback(const float* __restrict__ scores, const uint32_t* __restrict__ cov,
                           float* __restrict__ thr) {
    const int h = blockIdx.x;
    if (cov[h]) return;
    __shared__ uint32_t fh[NBINS_FB];
    __shared__ float fc[FILT_CAP];
    __shared__ uint32_t lcnt;
    __shared__ int sbin;
    __shared__ uint32_t sres;
    for (int i = threadIdx.x; i < NBINS_FB; i += blockDim.x) fh[i] = 0;
    if (threadIdx.x == 0) lcnt = 0;
    __syncthreads();
    const float* p = scores + (size_t)h * PER_HEAD;
    for (uint32_t i = threadIdx.x; i < PER_HEAD; i += blockDim.x) {
        float x = p[i];
        int b = (x < 1.0f) ? 0 : ((x >= 2.0f) ? (NBINS_FB - 1)
                                              : 1 + (int)((__float_as_uint(x) >> 12) & 0x7FFu));
        atomicAdd(&fh[b], 1u);
    }
    __syncthreads();
    if (threadIdx.x == 0) {
        uint64_t cum = 0; uint32_t res = 0; int b = 0;
        for (; b < NBINS_FB; ++b) {
            uint64_t nx = cum + fh[b];
            if ((uint64_t)K_SEL < nx) { res = (uint32_t)(K_SEL - cum); break; }
            cum = nx;
        }
        sbin = b; sres = res;
    }
    __syncthreads();
    const int tb = sbin;
    const uint32_t r2 = sres;
    for (uint32_t i = threadIdx.x; i < PER_HEAD; i += blockDim.x) {
        float x = p[i];
        int b = (x < 1.0f) ? 0 : ((x >= 2.0f) ? (NBINS_FB - 1)
                                              : 1 + (int)((__float_as_uint(x) >> 12) & 0x7FFu));
        if (b == tb) { uint32_t pos = atomicAdd(&lcnt, 1u); if (pos < FILT_CAP) fc[pos] = x; }
    }
    __syncthreads();
    const uint32_t m = min(lcnt, (uint32_t)FILT_CAP);
    for (uint32_t i = threadIdx.x; i < m; i += blockDim.x) {
        float x = fc[i];
        uint32_t less = 0, eq = 0;
        for (uint32_t j = 0; j < m; ++j) {
            float y = fc[j];
            less += (y < x);
            eq += (y == x);
        }
        if (less <= r2 && r2 < less + eq) thr[h] = x;
    }
}

__global__ void k_mask(const float* __restrict__ scores, const float* __restrict__ thr,
                       int* __restrict__ out) {
    const int h = blockIdx.y;
    __shared__ float st;
    if (threadIdx.x == 0) st = thr[h];
    __syncthreads();
    const float t = st;
    const float4v* p = (const float4v*)(scores + (size_t)h * PER_HEAD);
    int4v* o = (int4v*)(out + (size_t)h * PER_HEAD);
    const uint32_t nvec = PER_HEAD / 4;
    for (uint32_t i = blockIdx.x * blockDim.x + threadIdx.x; i < nvec;
         i += gridDim.x * blockDim.x) {
        float4v v = p[i];
        int4v m;
        m.x = (v.x >= t) ? 1 : 0;
        m.y = (v.y >= t) ? 1 : 0;
        m.z = (v.z >= t) ? 1 : 0;
        m.w = (v.w >= t) ? 1 : 0;
        __builtin_nontemporal_store(m, &o[i]);   // don't evict input from LLC
    }
}

extern "C" void kernel_launch(void* const* d_in, const int* in_sizes, int n_in,
                              void* d_out, int out_size, void* d_ws, size_t ws_size,
                              hipStream_t stream) {
    const float* scores = (const float*)d_in[0];
    int* out = (int*)d_out;
    uint8_t* ws = (uint8_t*)d_ws;

    uint32_t* below = (uint32_t*)ws;
    uint32_t* cnt   = (uint32_t*)(ws + OFF_CNT);
    uint32_t* cov   = (uint32_t*)(ws + OFF_COV);
    float*    thr   = (float*)(ws + OFF_THR);
    float*    cand  = (float*)(ws + OFF_CAND);

    dim3 blk(256);
    k_zero<<<1, 64, 0, stream>>>((uint32_t*)ws);
    k_hist<<<dim3(256, NUM_HEADS), blk, 0, stream>>>(scores, below, cnt, cand);
    k_select<<<NUM_HEADS, 256, 0, stream>>>(below, cnt, cand, cov, thr);
    k_fallback<<<NUM_HEADS, 256, 0, stream>>>(scores, cov, thr);
    k_mask<<<dim3(1024, NUM_HEADS), blk, 0, stream>>>(scores, thr, out);
}

// Round 7
// 164.457 us; speedup vs baseline: 14.4997x; 1.1299x over previous
//
#include <hip/hip_runtime.h>
#include <stdint.h>

// SparseAttentionMaskGenerator: per-(b,h) 0.95-quantile threshold mask.
// mask = scores >= x_(K_SEL) per head (0-indexed ascending order statistic);
// bit-exact vs jnp/np linear-interpolated quantile. Output: int32 0/1.
//
// Single full pass over the input (R6 had two):
//   k_pass1: read x once; write PROVISIONAL out = (x >= WEND); count
//            x < WSTART in registers; stage window elements (pos,val) via
//            LDS + one global atomic per block. Threshold provably lies in
//            [WSTART,WEND) whenever the exact coverage test passes, so only
//            window elements need fixing.
//   k_select: bin ~13K candidates/head (62 LDS bins), tie-aware rank select.
//   k_fallback_thr / k_maskfull: exact guarded fallback (never taken).
//   k_fix: out[pos] = (val >= thr[h]) for staged window elements only.
// Compulsory traffic: 256 MiB read + 256 MiB write + ~30 MB small = ~530 MiB.

#define NUM_HEADS 16
#define PER_HEAD (1u << 22)          // 2048*2048 per head
#define K_SEL 3984588u               // floor(0.95*(N-1)) + 1
#define WSTART 1.6298828125f         // 1 + 1290/2048 (exact float)
#define WEND   1.66015625f           // 1 + 1352/2048 (exact float)
#define WBIN0 1290
#define WBINS 62                     // quantile 1.6449 +- ~0.001; window +-15 bins
#define CAND_CAP 16384               // expected ~13.1K/head (29 sigma margin)
#define WBUF_CAP 384                 // per-block staging; lambda ~51
#define FILT_CAP 768                 // target-bin candidates ~210 expected
#define NBINS_FB 2050

typedef int   int4v   __attribute__((ext_vector_type(4)));
typedef float float4v __attribute__((ext_vector_type(4)));

// ws layout (bytes): below u32[16] @0, cnt u32[16] @64, ovf u32[16] @128,
//   cov u32[16] @192, thr f32[16] @256, cval f32[16][CAND_CAP] @320,
//   cpos u32[16][CAND_CAP] @320+1MiB.  Total ~2.1 MiB.
#define OFF_CNT   64
#define OFF_OVF   128
#define OFF_COV   192
#define OFF_THR   256
#define OFF_CVAL  320
#define OFF_CPOS  (320 + NUM_HEADS * CAND_CAP * 4)
#define ZERO_WORDS 64                // below+cnt+ovf+cov

__global__ void k_zero(uint32_t* __restrict__ ws) {
    if (threadIdx.x < ZERO_WORDS) ws[threadIdx.x] = 0u;
}

__global__ void k_pass1(const float* __restrict__ scores, int* __restrict__ out,
                        uint32_t* __restrict__ below, uint32_t* __restrict__ cnt,
                        uint32_t* __restrict__ ovf, uint32_t* __restrict__ cpos,
                        float* __restrict__ cval) {
    __shared__ uint32_t wpos[WBUF_CAP];
    __shared__ float    wval[WBUF_CAP];
    __shared__ uint32_t wcnt, wbase;
    __shared__ uint32_t wavesum[4];
    const int h = blockIdx.y;
    if (threadIdx.x == 0) wcnt = 0;
    __syncthreads();
    const float4v* p = (const float4v*)(scores + (size_t)h * PER_HEAD);
    int4v* o = (int4v*)(out + (size_t)h * PER_HEAD);
    const uint32_t nvec = PER_HEAD / 4;
    uint32_t nb = 0;
    for (uint32_t i = blockIdx.x * blockDim.x + threadIdx.x; i < nvec;
         i += gridDim.x * blockDim.x) {
        float4v v = p[i];
        int4v m;
#pragma unroll
        for (int j = 0; j < 4; ++j) {
            float x = v[j];
            m[j] = (x >= WEND) ? 1 : 0;          // provisional; window fixed later
            nb += (x < WSTART) ? 1u : 0u;
            if (x >= WSTART && x < WEND) {       // ~0.31% of elements
                uint32_t pos = atomicAdd(&wcnt, 1u);
                if (pos < WBUF_CAP) { wpos[pos] = i * 4u + j; wval[pos] = x; }
            }
        }
        __builtin_nontemporal_store(m, &o[i]);
    }
    // wave64 reduce + cross-wave LDS reduce of the below-count
#pragma unroll
    for (int off = 32; off > 0; off >>= 1) nb += __shfl_down(nb, off, 64);
    const int lane = threadIdx.x & 63, wid = threadIdx.x >> 6;
    if (lane == 0) wavesum[wid] = nb;
    __syncthreads();
    if (threadIdx.x == 0) {
        atomicAdd(&below[h], wavesum[0] + wavesum[1] + wavesum[2] + wavesum[3]);
        uint32_t nc = wcnt;
        if (nc > WBUF_CAP) atomicOr(&ovf[h], 1u);      // robust overflow flag
        wbase = atomicAdd(&cnt[h], min(nc, (uint32_t)WBUF_CAP));
    }
    __syncthreads();
    const uint32_t nc = min(wcnt, (uint32_t)WBUF_CAP);
    const uint32_t base = wbase;
    for (uint32_t i = threadIdx.x; i < nc; i += blockDim.x) {
        uint32_t pos = base + i;
        if (pos < CAND_CAP) {
            cpos[h * CAND_CAP + pos] = wpos[i];
            cval[h * CAND_CAP + pos] = wval[i];
        }
    }
}

__global__ void k_select(const uint32_t* __restrict__ below, const uint32_t* __restrict__ cnt,
                         const uint32_t* __restrict__ ovf, const float* __restrict__ cval,
                         uint32_t* __restrict__ cov, float* __restrict__ thr) {
    const int h = blockIdx.x;
    __shared__ uint32_t wh[WBINS];
    __shared__ float fc[FILT_CAP];
    __shared__ uint32_t lcnt, bad;
    __shared__ int sbin;
    __shared__ uint32_t sres;
    const uint32_t craw = cnt[h];
    const long long r = (long long)K_SEL - (long long)below[h];
    // exact coverage test: the K_SEL-th order statistic is among staged candidates
    if (ovf[h] || craw > CAND_CAP || r < 0 || r >= (long long)craw) {
        return;                                   // cov stays 0 -> fallback path
    }
    const uint32_t n = craw;
    for (int i = threadIdx.x; i < WBINS; i += blockDim.x) wh[i] = 0;
    if (threadIdx.x == 0) { lcnt = 0; bad = 0; }
    __syncthreads();
    for (uint32_t i = threadIdx.x; i < n; i += blockDim.x) {
        float x = cval[h * CAND_CAP + i];
        int b = (int)((__float_as_uint(x) >> 12) & 0x7FFu) - WBIN0;  // in [0,WBINS)
        atomicAdd(&wh[b], 1u);
    }
    __syncthreads();
    if (threadIdx.x == 0) {
        uint32_t cum = 0, res = 0;
        int b = 0;
        for (; b < WBINS; ++b) {
            uint32_t nx = cum + wh[b];
            if ((uint32_t)r < nx) { res = (uint32_t)r - cum; break; }
            cum = nx;
        }
        sbin = b; sres = res;
        if (wh[b] > FILT_CAP) bad = 1;            // paranoid: filter overflow
    }
    __syncthreads();
    if (bad) return;
    const int tb = sbin;
    const uint32_t r2 = sres;
    for (uint32_t i = threadIdx.x; i < n; i += blockDim.x) {
        float x = cval[h * CAND_CAP + i];
        int b = (int)((__float_as_uint(x) >> 12) & 0x7FFu) - WBIN0;
        if (b == tb) { uint32_t pos = atomicAdd(&lcnt, 1u); if (pos < FILT_CAP) fc[pos] = x; }
    }
    __syncthreads();
    const uint32_t m = lcnt;   // == wh[tb] <= FILT_CAP
    // Tie-aware rank selection — order-independent of append order.
    for (uint32_t i = threadIdx.x; i < m; i += blockDim.x) {
        float x = fc[i];
        uint32_t less = 0, eq = 0;
        for (uint32_t j = 0; j < m; ++j) {
            float y = fc[j];
            less += (y < x);
            eq += (y == x);
        }
        if (less <= r2 && r2 < less + eq) thr[h] = x;
    }
    __syncthreads();
    if (threadIdx.x == 0) cov[h] = 1u;
}

// Exact per-head threshold fallback; never taken for this input (cov margin
// ~15 sigma). One block rescans its head twice via 2050-bin LDS histogram.
__global__ void k_fallback_thr(const float* __restrict__ scores, const uint32_t* __restrict__ cov,
                               float* __restrict__ thr) {
    const int h = blockIdx.x;
    if (cov[h]) return;
    __shared__ uint32_t fh[NBINS_FB];
    __shared__ float fc[FILT_CAP];
    __shared__ uint32_t lcnt;
    __shared__ int sbin;
    __shared__ uint32_t sres;
    for (int i = threadIdx.x; i < NBINS_FB; i += blockDim.x) fh[i] = 0;
    if (threadIdx.x == 0) lcnt = 0;
    __syncthreads();
    const float* p = scores + (size_t)h * PER_HEAD;
    for (uint32_t i = threadIdx.x; i < PER_HEAD; i += blockDim.x) {
        float x = p[i];
        int b = (x < 1.0f) ? 0 : ((x >= 2.0f) ? (NBINS_FB - 1)
                                              : 1 + (int)((__float_as_uint(x) >> 12) & 0x7FFu));
        atomicAdd(&fh[b], 1u);
    }
    __syncthreads();
    if (threadIdx.x == 0) {
        uint64_t cum = 0; uint32_t res = 0; int b = 0;
        for (; b < NBINS_FB; ++b) {
            uint64_t nx = cum + fh[b];
            if ((uint64_t)K_SEL < nx) { res = (uint32_t)(K_SEL - cum); break; }
            cum = nx;
        }
        sbin = b; sres = res;
    }
    __syncthreads();
    const int tb = sbin;
    const uint32_t r2 = sres;
    for (uint32_t i = threadIdx.x; i < PER_HEAD; i += blockDim.x) {
        float x = p[i];
        int b = (x < 1.0f) ? 0 : ((x >= 2.0f) ? (NBINS_FB - 1)
                                              : 1 + (int)((__float_as_uint(x) >> 12) & 0x7FFu));
        if (b == tb) { uint32_t pos = atomicAdd(&lcnt, 1u); if (pos < FILT_CAP) fc[pos] = x; }
    }
    __syncthreads();
    const uint32_t m = min(lcnt, (uint32_t)FILT_CAP);
    for (uint32_t i = threadIdx.x; i < m; i += blockDim.x) {
        float x = fc[i];
        uint32_t less = 0, eq = 0;
        for (uint32_t j = 0; j < m; ++j) {
            float y = fc[j];
            less += (y < x);
            eq += (y == x);
        }
        if (less <= r2 && r2 < less + eq) thr[h] = x;
    }
}

// Guarded full mask recompute — no-op when covered (the expected case).
__global__ void k_maskfull(const float* __restrict__ scores, const uint32_t* __restrict__ cov,
                           const float* __restrict__ thr, int* __restrict__ out) {
    const int h = blockIdx.y;
    if (cov[h]) return;
    const float t = thr[h];
    const float4v* p = (const float4v*)(scores + (size_t)h * PER_HEAD);
    int4v* o = (int4v*)(out + (size_t)h * PER_HEAD);
    const uint32_t nvec = PER_HEAD / 4;
    for (uint32_t i = blockIdx.x * blockDim.x + threadIdx.x; i < nvec;
         i += gridDim.x * blockDim.x) {
        float4v v = p[i];
        int4v m;
        m.x = (v.x >= t) ? 1 : 0;
        m.y = (v.y >= t) ? 1 : 0;
        m.z = (v.z >= t) ? 1 : 0;
        m.w = (v.w >= t) ? 1 : 0;
        o[i] = m;
    }
}

// Fix the staged window positions with the final threshold (covered heads only).
__global__ void k_fix(const uint32_t* __restrict__ cnt, const uint32_t* __restrict__ cov,
                      const uint32_t* __restrict__ cpos, const float* __restrict__ cval,
                      const float* __restrict__ thr, int* __restrict__ out) {
    const int h = blockIdx.y;
    if (!cov[h]) return;                          // uncovered -> k_maskfull rewrote all
    const uint32_t n = min(cnt[h], (uint32_t)CAND_CAP);
    const float t = thr[h];
    int* oh = out + (size_t)h * PER_HEAD;
    for (uint32_t i = blockIdx.x * blockDim.x + threadIdx.x; i < n;
         i += gridDim.x * blockDim.x) {
        oh[cpos[h * CAND_CAP + i]] = (cval[h * CAND_CAP + i] >= t) ? 1 : 0;
    }
}

extern "C" void kernel_launch(void* const* d_in, const int* in_sizes, int n_in,
                              void* d_out, int out_size, void* d_ws, size_t ws_size,
                              hipStream_t stream) {
    const float* scores = (const float*)d_in[0];
    int* out = (int*)d_out;
    uint8_t* ws = (uint8_t*)d_ws;

    uint32_t* below = (uint32_t*)ws;
    uint32_t* cnt   = (uint32_t*)(ws + OFF_CNT);
    uint32_t* ovf   = (uint32_t*)(ws + OFF_OVF);
    uint32_t* cov   = (uint32_t*)(ws + OFF_COV);
    float*    thr   = (float*)(ws + OFF_THR);
    float*    cval  = (float*)(ws + OFF_CVAL);
    uint32_t* cpos  = (uint32_t*)(ws + OFF_CPOS);

    dim3 blk(256);
    k_zero<<<1, 64, 0, stream>>>((uint32_t*)ws);
    k_pass1<<<dim3(256, NUM_HEADS), blk, 0, stream>>>(scores, out, below, cnt, ovf, cpos, cval);
    k_select<<<NUM_HEADS, 256, 0, stream>>>(below, cnt, ovf, cval, cov, thr);
    k_fallback_thr<<<NUM_HEADS, 256, 0, stream>>>(scores, cov, thr);
    k_maskfull<<<dim3(256, NUM_HEADS), blk, 0, stream>>>(scores, cov, thr, out);
    k_fix<<<dim3(8, NUM_HEADS), blk, 0, stream>>>(cnt, cov, cpos, cval, thr, out);
}